// Round 3
// baseline (1029.823 us; speedup 1.0000x reference)
//
#include <hip/hip_runtime.h>
#include <hip/hip_bf16.h>
#include <stdint.h>

typedef unsigned short ushort_t;
typedef uint32_t u32;
typedef __attribute__((ext_vector_type(8))) __bf16 bf16x8;
typedef __attribute__((ext_vector_type(8))) unsigned short u16x8;
typedef __attribute__((ext_vector_type(4))) float f32x4;

#define T_  256
#define H_  2048
#define E_  60
#define F_  1408
#define FS_ 5632

__device__ __forceinline__ u32 rne2(float lo, float hi){
  u32 a = __builtin_bit_cast(u32, lo);
  u32 b = __builtin_bit_cast(u32, hi);
  a += 0x7FFFu + ((a >> 16) & 1u);
  b += 0x7FFFu + ((b >> 16) & 1u);
  return (a >> 16) | (b & 0xFFFF0000u);
}
__device__ __forceinline__ ushort_t rne1(float f){
  u32 a = __builtin_bit_cast(u32, f);
  a += 0x7FFFu + ((a >> 16) & 1u);
  return (ushort_t)(a >> 16);
}
__device__ __forceinline__ f32x4 zero4(){ f32x4 z; z[0]=0.f; z[1]=0.f; z[2]=0.f; z[3]=0.f; return z; }

// B-operand fragment for mfma_f32_16x16x32_bf16: lane holds B[kb+e][col], e=0..7.
// p points at W[kb][col] (per-lane), ld = row stride in elements. 8 strided dwords,
// converted f32->bf16 (RNE) and packed.
__device__ __forceinline__ bf16x8 loadb(const float* p, int ld){
  union { u32 u[4]; bf16x8 v; } cv;
  cv.u[0] = rne2(p[0],    p[ld]);
  cv.u[1] = rne2(p[2*ld], p[3*ld]);
  cv.u[2] = rne2(p[4*ld], p[5*ld]);
  cv.u[3] = rne2(p[6*ld], p[7*ld]);
  return cv.v;
}
__device__ __forceinline__ bf16x8 loada(const ushort_t* p){
  return __builtin_bit_cast(bf16x8, *(const u16x8*)p);
}
#define MFMA(a,b,c) __builtin_amdgcn_mfma_f32_16x16x32_bf16((a),(b),(c),0,0,0)

// ---------------- K1: router (f32 logits -> top4 + vals), sigmoid gate, x->bf16 ----
__global__ __launch_bounds__(256) void k_router(
    const float* __restrict__ x, const float* __restrict__ gw,
    const float* __restrict__ sgw, ushort_t* __restrict__ xb,
    int* __restrict__ tk_idx, float* __restrict__ tk_val, float* __restrict__ sig)
{
  const int t = blockIdx.x, tid = threadIdx.x;
  const float* xr = x + (size_t)t * H_;
  // x -> bf16 (8 elems/thread)
  {
    const float4 v0 = *(const float4*)(xr + tid*8);
    const float4 v1 = *(const float4*)(xr + tid*8 + 4);
    u32* dst = (u32*)(xb + (size_t)t*H_ + tid*8);
    dst[0] = rne2(v0.x, v0.y); dst[1] = rne2(v0.z, v0.w);
    dst[2] = rne2(v1.x, v1.y); dst[3] = rne2(v1.z, v1.w);
  }
  __shared__ float s_part[4][64];
  __shared__ float s_logit[64];
  __shared__ float s_red[256];
  const int e = tid & 63, q = tid >> 6;
  float p = 0.f;
  if (e < E_) {
    const float* g = gw + e;
    for (int h = q*512; h < q*512 + 512; ++h) p += xr[h] * g[h*E_];
  }
  s_part[q][e] = p;
  float sp = 0.f;
  for (int h = tid; h < H_; h += 256) sp += xr[h] * sgw[h];
  s_red[tid] = sp;
  __syncthreads();
  if (tid < 64) s_logit[tid] = s_part[0][tid] + s_part[1][tid] + s_part[2][tid] + s_part[3][tid];
  for (int s = 128; s > 0; s >>= 1) {
    if (tid < s) s_red[tid] += s_red[tid + s];
    __syncthreads();
  }
  if (tid == 0) {
    sig[t] = 1.f / (1.f + expf(-s_red[0]));
    float mx = -3.4e38f;
    for (int i = 0; i < E_; ++i) mx = fmaxf(mx, s_logit[i]);
    float sum = 0.f;
    for (int i = 0; i < E_; ++i) sum += expf(s_logit[i] - mx);
    for (int k = 0; k < 4; ++k) {
      float bv = -3.4e38f; int bi = 0;
      for (int i = 0; i < E_; ++i) { float v = s_logit[i]; if (v > bv) { bv = v; bi = i; } }
      tk_idx[t*4 + k] = bi;
      tk_val[t*4 + k] = expf(bv - mx) / sum;
      s_logit[bi] = -3.4e38f;
    }
  }
}

// ---------------- K2: per-expert token lists (deterministic, no atomics) ----------
__global__ void k_lists(const int* __restrict__ tk_idx, const float* __restrict__ tk_val,
                        int* __restrict__ cnt, int* __restrict__ ltok,
                        int* __restrict__ lpair, float* __restrict__ lwt)
{
  const int e = threadIdx.x;
  if (e >= E_) return;
  int c = 0;
  for (int t = 0; t < T_; ++t) {
    #pragma unroll
    for (int k = 0; k < 4; ++k) {
      int ei = tk_idx[t*4 + k];
      if (ei == e && c < 64) {
        ltok[e*64 + c] = t;
        lpair[e*64 + c] = t*4 + k;
        lwt[e*64 + c] = tk_val[t*4 + k];
        ++c;
      }
    }
  }
  cnt[e] = c;
}

// ---------------- K3: MoE gate/up. tile M=32 tokens, N=128 (4 waves x 32) ---------
__global__ __launch_bounds__(256) void k_moe_gu(
    const ushort_t* __restrict__ xb, const float* __restrict__ wg_all,
    const float* __restrict__ wu_all, const int* __restrict__ cnt,
    const int* __restrict__ ltok, const float* __restrict__ lwt,
    ushort_t* __restrict__ act)
{
  const int e = blockIdx.y;
  const int m = cnt[e];
  const int c0 = blockIdx.z * 32;
  if (c0 >= m) return;
  const int tid = threadIdx.x, wave = tid >> 6, lane = tid & 63;
  __shared__ int s_tok[32];
  __shared__ float s_wt[32];
  if (tid < 32) {
    int i = c0 + tid;
    s_tok[tid] = ltok[e*64 + ((i < m) ? i : c0)];
    s_wt[tid]  = (i < m) ? lwt[e*64 + i] : 0.f;
  }
  __syncthreads();
  const int col0 = blockIdx.x * 128 + wave * 32;
  const int ln15 = lane & 15, kg = lane >> 4;
  const size_t wbase = (size_t)e * ((size_t)H_ * F_);
  const ushort_t* a0p = xb + (size_t)s_tok[ln15] * H_ + kg*8;
  const ushort_t* a1p = xb + (size_t)s_tok[16 + ln15] * H_ + kg*8;
  const float* bg0 = wg_all + wbase + (size_t)(kg*8) * F_ + col0 + ln15;
  const float* bg1 = bg0 + 16;
  const float* bu0 = wu_all + wbase + (size_t)(kg*8) * F_ + col0 + ln15;
  const float* bu1 = bu0 + 16;
  f32x4 accg[2][2], accu[2][2];
  for (int i = 0; i < 2; ++i) for (int j = 0; j < 2; ++j) { accg[i][j] = zero4(); accu[i][j] = zero4(); }
  for (int k0 = 0; k0 < H_; k0 += 32) {
    bf16x8 a0 = loada(a0p + k0);
    bf16x8 a1 = loada(a1p + k0);
    bf16x8 g0 = loadb(bg0, F_), g1 = loadb(bg1, F_);
    bf16x8 u0 = loadb(bu0, F_), u1 = loadb(bu1, F_);
    accg[0][0] = MFMA(a0, g0, accg[0][0]);
    accg[1][0] = MFMA(a1, g0, accg[1][0]);
    accg[0][1] = MFMA(a0, g1, accg[0][1]);
    accg[1][1] = MFMA(a1, g1, accg[1][1]);
    accu[0][0] = MFMA(a0, u0, accu[0][0]);
    accu[1][0] = MFMA(a1, u0, accu[1][0]);
    accu[0][1] = MFMA(a0, u1, accu[0][1]);
    accu[1][1] = MFMA(a1, u1, accu[1][1]);
    bg0 += 32*F_; bg1 += 32*F_; bu0 += 32*F_; bu1 += 32*F_;
  }
  #pragma unroll
  for (int mt = 0; mt < 2; ++mt)
    #pragma unroll
    for (int nt = 0; nt < 2; ++nt)
      #pragma unroll
      for (int j = 0; j < 4; ++j) {
        int r = mt*16 + kg*4 + j;
        int i = c0 + r;
        if (i < m) {
          float g = accg[mt][nt][j], u = accu[mt][nt][j];
          float a = g / (1.f + __expf(-g)) * u * s_wt[r];
          act[((size_t)e*64 + i) * F_ + col0 + nt*16 + ln15] = rne1(a);
        }
      }
}

// ---------------- K4: MoE down. out4[pair][H] f32, no atomics ---------------------
__global__ __launch_bounds__(256) void k_moe_down(
    const ushort_t* __restrict__ act, const float* __restrict__ wd_all,
    const int* __restrict__ cnt, const int* __restrict__ lpair,
    float* __restrict__ out4)
{
  const int e = blockIdx.y;
  const int m = cnt[e];
  const int c0 = blockIdx.z * 32;
  if (c0 >= m) return;
  const int tid = threadIdx.x, wave = tid >> 6, lane = tid & 63;
  __shared__ int s_pair[32];
  if (tid < 32) { int i = c0 + tid; s_pair[tid] = (i < m) ? lpair[e*64 + i] : 0; }
  __syncthreads();
  const int col0 = blockIdx.x * 128 + wave * 32;
  const int ln15 = lane & 15, kg = lane >> 4;
  const ushort_t* a0p = act + ((size_t)e*64 + c0 + ln15) * F_ + kg*8;
  const ushort_t* a1p = a0p + (size_t)16 * F_;
  const float* b0 = wd_all + (size_t)e * ((size_t)F_ * H_) + (size_t)(kg*8) * H_ + col0 + ln15;
  const float* b1 = b0 + 16;
  f32x4 ac[2][2];
  for (int i = 0; i < 2; ++i) for (int j = 0; j < 2; ++j) ac[i][j] = zero4();
  for (int k0 = 0; k0 < F_; k0 += 32) {
    bf16x8 a0 = loada(a0p + k0);
    bf16x8 a1 = loada(a1p + k0);
    bf16x8 w0 = loadb(b0, H_), w1 = loadb(b1, H_);
    ac[0][0] = MFMA(a0, w0, ac[0][0]);
    ac[1][0] = MFMA(a1, w0, ac[1][0]);
    ac[0][1] = MFMA(a0, w1, ac[0][1]);
    ac[1][1] = MFMA(a1, w1, ac[1][1]);
    b0 += 32*H_; b1 += 32*H_;
  }
  #pragma unroll
  for (int mt = 0; mt < 2; ++mt)
    #pragma unroll
    for (int nt = 0; nt < 2; ++nt)
      #pragma unroll
      for (int j = 0; j < 4; ++j) {
        int r = mt*16 + kg*4 + j;
        int i = c0 + r;
        if (i < m)
          out4[(size_t)s_pair[r] * H_ + col0 + nt*16 + ln15] = ac[mt][nt][j];
      }
}

// ---------------- K5: shared gate/up. M=256 (4 waves x 64 rows), N=16/block -------
__global__ __launch_bounds__(256) void k_sh_gu(
    const ushort_t* __restrict__ xb, const float* __restrict__ swg,
    const float* __restrict__ swu, ushort_t* __restrict__ acts)
{
  const int tid = threadIdx.x, wave = tid >> 6, lane = tid & 63;
  const int ln15 = lane & 15, kg = lane >> 4;
  const int fb = blockIdx.x * 16;
  const int rowb = wave * 64;
  const ushort_t* ap[4];
  #pragma unroll
  for (int mt = 0; mt < 4; ++mt) ap[mt] = xb + (size_t)(rowb + mt*16 + ln15) * H_ + kg*8;
  const float* pg = swg + (size_t)(kg*8) * FS_ + fb + ln15;
  const float* pu = swu + (size_t)(kg*8) * FS_ + fb + ln15;
  f32x4 ag[4], au[4];
  for (int i = 0; i < 4; ++i) { ag[i] = zero4(); au[i] = zero4(); }
  for (int k0 = 0; k0 < H_; k0 += 32) {
    bf16x8 bg = loadb(pg, FS_);
    bf16x8 bu = loadb(pu, FS_);
    #pragma unroll
    for (int mt = 0; mt < 4; ++mt) {
      bf16x8 a = loada(ap[mt] + k0);
      ag[mt] = MFMA(a, bg, ag[mt]);
      au[mt] = MFMA(a, bu, au[mt]);
    }
    pg += 32*FS_; pu += 32*FS_;
  }
  #pragma unroll
  for (int mt = 0; mt < 4; ++mt)
    #pragma unroll
    for (int j = 0; j < 4; ++j) {
      int row = rowb + mt*16 + kg*4 + j;
      float g = ag[mt][j], u = au[mt][j];
      acts[(size_t)row * FS_ + fb + ln15] = rne1(g / (1.f + __expf(-g)) * u);
    }
}

// ---------------- K6: shared down, K split in 2 halves -> acc2[2][T][H] -----------
__global__ __launch_bounds__(256) void k_sh_down(
    const ushort_t* __restrict__ acts, const float* __restrict__ swd,
    float* __restrict__ acc2)
{
  const int tid = threadIdx.x, wave = tid >> 6, lane = tid & 63;
  const int ln15 = lane & 15, kg = lane >> 4;
  const int hb = blockIdx.x * 16;
  const int kh = blockIdx.y;           // 0/1 : k in [kh*2816, kh*2816+2816)
  const int rowb = wave * 64;
  const ushort_t* ap[4];
  #pragma unroll
  for (int mt = 0; mt < 4; ++mt)
    ap[mt] = acts + (size_t)(rowb + mt*16 + ln15) * FS_ + kh*2816 + kg*8;
  const float* pb = swd + (size_t)(kh*2816 + kg*8) * H_ + hb + ln15;
  f32x4 ac[4];
  for (int i = 0; i < 4; ++i) ac[i] = zero4();
  for (int k0 = 0; k0 < 2816; k0 += 32) {
    bf16x8 b = loadb(pb, H_);
    #pragma unroll
    for (int mt = 0; mt < 4; ++mt) {
      bf16x8 a = loada(ap[mt] + k0);
      ac[mt] = MFMA(a, b, ac[mt]);
    }
    pb += 32*H_;
  }
  #pragma unroll
  for (int mt = 0; mt < 4; ++mt)
    #pragma unroll
    for (int j = 0; j < 4; ++j) {
      int row = rowb + mt*16 + kg*4 + j;
      acc2[((size_t)kh * T_ + row) * H_ + hb + ln15] = ac[mt][j];
    }
}

// ---------------- K7: combine: sigmoid-gated shared + 4 expert slots -> f32 out ----
__global__ __launch_bounds__(256) void k_final(
    const float* __restrict__ acc2, const float* __restrict__ out4,
    const float* __restrict__ sig, float* __restrict__ out)
{
  const int idx = blockIdx.x * blockDim.x + threadIdx.x;  // 131072 threads, 4 elems each
  const int t = idx >> 9;
  const int h = (idx & 511) * 4;
  const float4 s0 = *(const float4*)(acc2 + (size_t)t * H_ + h);
  const float4 s1 = *(const float4*)(acc2 + ((size_t)T_ + t) * H_ + h);
  const float sg = sig[t];
  float ox = sg * (s0.x + s1.x), oy = sg * (s0.y + s1.y);
  float oz = sg * (s0.z + s1.z), ow = sg * (s0.w + s1.w);
  #pragma unroll
  for (int k = 0; k < 4; ++k) {
    const float4 e4 = *(const float4*)(out4 + (size_t)(t*4 + k) * H_ + h);
    ox += e4.x; oy += e4.y; oz += e4.z; ow += e4.w;
  }
  float4 o; o.x = ox; o.y = oy; o.z = oz; o.w = ow;
  *(float4*)(out + (size_t)t * H_ + h) = o;
}

// ---------------- launch -----------------------------------------------------------
extern "C" void kernel_launch(void* const* d_in, const int* in_sizes, int n_in,
                              void* d_out, int out_size, void* d_ws, size_t ws_size,
                              hipStream_t stream)
{
  (void)in_sizes; (void)n_in; (void)out_size; (void)ws_size;
  const float* x   = (const float*)d_in[0];
  const float* gw  = (const float*)d_in[1];
  const float* wg  = (const float*)d_in[2];
  const float* wu  = (const float*)d_in[3];
  const float* wd  = (const float*)d_in[4];
  const float* swg = (const float*)d_in[5];
  const float* swu = (const float*)d_in[6];
  const float* swd = (const float*)d_in[7];
  const float* sgw = (const float*)d_in[8];

  char* ws = (char*)d_ws;
  ushort_t* xb    = (ushort_t*)(ws);                 // 256*2048*2        = 1,048,576
  ushort_t* act   = (ushort_t*)(ws + 1048576);       // 60*64*1408*2     = 10,813,440
  ushort_t* acts  = (ushort_t*)(ws + 11862016);      // 256*5632*2       = 2,883,584
  float*    out4  = (float*)   (ws + 14745600);      // 1024*2048*4      = 8,388,608
  float*    acc2  = (float*)   (ws + 23134208);      // 2*256*2048*4     = 4,194,304
  float*    sig   = (float*)   (ws + 27328512);      // 256*4
  int*      tkidx = (int*)     (ws + 27329536);      // 256*4*4
  float*    tkval = (float*)   (ws + 27333632);      // 256*4*4
  int*      cnt   = (int*)     (ws + 27337728);      // 60*4 (pad 256)
  int*      ltok  = (int*)     (ws + 27337984);      // 60*64*4
  int*      lpair = (int*)     (ws + 27353344);      // 60*64*4
  float*    lwt   = (float*)   (ws + 27368704);      // 60*64*4

  k_router  <<<T_, 256, 0, stream>>>(x, gw, sgw, xb, tkidx, tkval, sig);
  k_lists   <<<1, 64, 0, stream>>>(tkidx, tkval, cnt, ltok, lpair, lwt);
  k_moe_gu  <<<dim3(F_/128, E_, 2), 256, 0, stream>>>(xb, wg, wu, cnt, ltok, lwt, act);
  k_moe_down<<<dim3(H_/128, E_, 2), 256, 0, stream>>>(act, wd, cnt, lpair, out4);
  k_sh_gu   <<<dim3(FS_/16), 256, 0, stream>>>(xb, swg, swu, acts);
  k_sh_down <<<dim3(H_/16, 2), 256, 0, stream>>>(acts, swd, acc2);
  k_final   <<<512, 256, 0, stream>>>(acc2, out4, sig, (float*)d_out);
}

// Round 4
// 798.867 us; speedup vs baseline: 1.2891x; 1.2891x over previous
//
#include <hip/hip_runtime.h>
#include <hip/hip_bf16.h>
#include <stdint.h>

typedef unsigned short ushort_t;
typedef uint32_t u32;
typedef __attribute__((ext_vector_type(8))) __bf16 bf16x8;
typedef __attribute__((ext_vector_type(8))) unsigned short u16x8;
typedef __attribute__((ext_vector_type(4))) float f32x4;

#define T_  256
#define H_  2048
#define E_  60
#define F_  1408
#define FS_ 5632

__device__ __forceinline__ u32 rne2(float lo, float hi){
  u32 a = __builtin_bit_cast(u32, lo);
  u32 b = __builtin_bit_cast(u32, hi);
  a += 0x7FFFu + ((a >> 16) & 1u);
  b += 0x7FFFu + ((b >> 16) & 1u);
  return (a >> 16) | (b & 0xFFFF0000u);
}
__device__ __forceinline__ ushort_t rne1(float f){
  u32 a = __builtin_bit_cast(u32, f);
  a += 0x7FFFu + ((a >> 16) & 1u);
  return (ushort_t)(a >> 16);
}
__device__ __forceinline__ f32x4 zero4(){ f32x4 z; z[0]=0.f; z[1]=0.f; z[2]=0.f; z[3]=0.f; return z; }

// strided-global B fragment (still used by shared-expert kernels)
__device__ __forceinline__ bf16x8 loadb(const float* p, int ld){
  union { u32 u[4]; bf16x8 v; } cv;
  cv.u[0] = rne2(p[0],    p[ld]);
  cv.u[1] = rne2(p[2*ld], p[3*ld]);
  cv.u[2] = rne2(p[4*ld], p[5*ld]);
  cv.u[3] = rne2(p[6*ld], p[7*ld]);
  return cv.v;
}
__device__ __forceinline__ bf16x8 loada(const ushort_t* p){
  return __builtin_bit_cast(bf16x8, *(const u16x8*)p);
}
// B fragment from LDS f32 tile, row stride 128 floats; p -> [row kg*8][col]
__device__ __forceinline__ bf16x8 ldsb(const float* p){
  union { u32 u[4]; bf16x8 v; } cv;
  cv.u[0] = rne2(p[0],   p[128]);
  cv.u[1] = rne2(p[256], p[384]);
  cv.u[2] = rne2(p[512], p[640]);
  cv.u[3] = rne2(p[768], p[896]);
  return cv.v;
}
// async global->LDS, 16B/lane, dest = wave-uniform base + lane*16
__device__ __forceinline__ void gload16(const float* g, float* l){
  __builtin_amdgcn_global_load_lds(
      (const __attribute__((address_space(1))) void*)g,
      (__attribute__((address_space(3))) void*)l, 16, 0, 0);
}
#define MFMA(a,b,c) __builtin_amdgcn_mfma_f32_16x16x32_bf16((a),(b),(c),0,0,0)

// ---------------- K1: router (f32 logits -> top4 + vals), sigmoid gate, x->bf16 ----
__global__ __launch_bounds__(256) void k_router(
    const float* __restrict__ x, const float* __restrict__ gw,
    const float* __restrict__ sgw, ushort_t* __restrict__ xb,
    int* __restrict__ tk_idx, float* __restrict__ tk_val, float* __restrict__ sig)
{
  const int t = blockIdx.x, tid = threadIdx.x;
  const float* xr = x + (size_t)t * H_;
  {
    const float4 v0 = *(const float4*)(xr + tid*8);
    const float4 v1 = *(const float4*)(xr + tid*8 + 4);
    u32* dst = (u32*)(xb + (size_t)t*H_ + tid*8);
    dst[0] = rne2(v0.x, v0.y); dst[1] = rne2(v0.z, v0.w);
    dst[2] = rne2(v1.x, v1.y); dst[3] = rne2(v1.z, v1.w);
  }
  __shared__ float s_part[4][64];
  __shared__ float s_logit[64];
  __shared__ float s_red[256];
  const int e = tid & 63, q = tid >> 6;
  float p = 0.f;
  if (e < E_) {
    const float* g = gw + e;
    for (int h = q*512; h < q*512 + 512; ++h) p += xr[h] * g[h*E_];
  }
  s_part[q][e] = p;
  float sp = 0.f;
  for (int h = tid; h < H_; h += 256) sp += xr[h] * sgw[h];
  s_red[tid] = sp;
  __syncthreads();
  if (tid < 64) s_logit[tid] = s_part[0][tid] + s_part[1][tid] + s_part[2][tid] + s_part[3][tid];
  for (int s = 128; s > 0; s >>= 1) {
    if (tid < s) s_red[tid] += s_red[tid + s];
    __syncthreads();
  }
  if (tid == 0) {
    sig[t] = 1.f / (1.f + expf(-s_red[0]));
    float mx = -3.4e38f;
    for (int i = 0; i < E_; ++i) mx = fmaxf(mx, s_logit[i]);
    float sum = 0.f;
    for (int i = 0; i < E_; ++i) sum += expf(s_logit[i] - mx);
    for (int k = 0; k < 4; ++k) {
      float bv = -3.4e38f; int bi = 0;
      for (int i = 0; i < E_; ++i) { float v = s_logit[i]; if (v > bv) { bv = v; bi = i; } }
      tk_idx[t*4 + k] = bi;
      tk_val[t*4 + k] = expf(bv - mx) / sum;
      s_logit[bi] = -3.4e38f;
    }
  }
}

// ---------------- K2: per-expert token lists (deterministic, no atomics) ----------
__global__ void k_lists(const int* __restrict__ tk_idx, const float* __restrict__ tk_val,
                        int* __restrict__ cnt, int* __restrict__ ltok,
                        int* __restrict__ lpair, float* __restrict__ lwt)
{
  const int e = threadIdx.x;
  if (e >= E_) return;
  int c = 0;
  for (int t = 0; t < T_; ++t) {
    #pragma unroll
    for (int k = 0; k < 4; ++k) {
      int ei = tk_idx[t*4 + k];
      if (ei == e && c < 64) {
        ltok[e*64 + c] = t;
        lpair[e*64 + c] = t*4 + k;
        lwt[e*64 + c] = tk_val[t*4 + k];
        ++c;
      }
    }
  }
  cnt[e] = c;
}

// ---------------- K3: MoE gate/up, LDS-staged weights, M=64, N=128 ----------------
// grid (F/128, E); 4 waves; LDS = 2 buf x (Wg[32][128] + Wu[32][128]) f32 = 64KB
__global__ __launch_bounds__(256) void k_moe_gu(
    const ushort_t* __restrict__ xb, const float* __restrict__ wg_all,
    const float* __restrict__ wu_all, const int* __restrict__ cnt,
    const int* __restrict__ ltok, const float* __restrict__ lwt,
    ushort_t* __restrict__ act)
{
  __shared__ float lds[2][2*32*128];       // exactly 65536 B
  const int e = blockIdx.y;
  int m = cnt[e];
  if (m == 0) return;
  if (m > 64) m = 64;
  const int tid = threadIdx.x, wave = tid >> 6, lane = tid & 63;
  const int ln15 = lane & 15, kg = lane >> 4;
  const int col0 = blockIdx.x * 128;
  const size_t wbase = (size_t)e * ((size_t)H_ * F_) + col0;
  const float* gsg = wg_all + wbase;
  const float* gsu = wu_all + wbase;
  const int srl = lane >> 5, scl = (lane & 31) * 4;  // staging: row-sub, col(float)
  const int r0 = wave * 8;

  // A pointers (token list read direct from global; padded rows duplicate last)
  const ushort_t* ap[4];
  #pragma unroll
  for (int rt = 0; rt < 4; ++rt) {
    int row = rt*16 + ln15;
    int tok = ltok[e*64 + (row < m ? row : m-1)];
    ap[rt] = xb + (size_t)tok * H_ + kg*8;
  }

  f32x4 ag[4][2], au[4][2];
  #pragma unroll
  for (int i = 0; i < 4; ++i) { ag[i][0]=zero4(); ag[i][1]=zero4(); au[i][0]=zero4(); au[i][1]=zero4(); }

  // prologue: stage k0=0 into buf 0 (wave stages its 8 rows of each tile)
  #pragma unroll
  for (int i2 = 0; i2 < 4; ++i2) {
    int r = r0 + i2*2;
    gload16(gsg + (size_t)(r + srl)*F_ + scl, &lds[0][r*128]);
    gload16(gsu + (size_t)(r + srl)*F_ + scl, &lds[0][32*128 + r*128]);
  }
  __syncthreads();

  int cur = 0;
  for (int k0 = 0; k0 < H_; k0 += 32) {
    const int nxt = cur ^ 1;
    if (k0 + 32 < H_) {
      const float* gg = gsg + (size_t)(k0+32) * F_;
      const float* gu = gsu + (size_t)(k0+32) * F_;
      #pragma unroll
      for (int i2 = 0; i2 < 4; ++i2) {
        int r = r0 + i2*2;
        gload16(gg + (size_t)(r + srl)*F_ + scl, &lds[nxt][r*128]);
        gload16(gu + (size_t)(r + srl)*F_ + scl, &lds[nxt][32*128 + r*128]);
      }
    }
    // compute from lds[cur]
    bf16x8 a[4];
    #pragma unroll
    for (int rt = 0; rt < 4; ++rt) a[rt] = loada(ap[rt] + k0);
    const float* lg = &lds[cur][wave*32 + ln15 + kg*8*128];
    const float* lu = lg + 32*128;
    bf16x8 bg0 = ldsb(lg), bg1 = ldsb(lg + 16);
    bf16x8 bu0 = ldsb(lu), bu1 = ldsb(lu + 16);
    #pragma unroll
    for (int rt = 0; rt < 4; ++rt) {
      ag[rt][0] = MFMA(a[rt], bg0, ag[rt][0]);
      ag[rt][1] = MFMA(a[rt], bg1, ag[rt][1]);
      au[rt][0] = MFMA(a[rt], bu0, au[rt][0]);
      au[rt][1] = MFMA(a[rt], bu1, au[rt][1]);
    }
    __syncthreads();
    cur = nxt;
  }

  #pragma unroll
  for (int rt = 0; rt < 4; ++rt)
    #pragma unroll
    for (int nt = 0; nt < 2; ++nt)
      #pragma unroll
      for (int j = 0; j < 4; ++j) {
        int r = rt*16 + kg*4 + j;
        if (r < m) {
          float wt = lwt[e*64 + r];
          float g = ag[rt][nt][j], u = au[rt][nt][j];
          float a = g / (1.f + __expf(-g)) * u * wt;
          act[((size_t)e*64 + r) * F_ + col0 + wave*32 + nt*16 + ln15] = rne1(a);
        }
      }
}

// ---------------- K4: MoE down, LDS-staged weights, M=64, N=128 -------------------
// grid (H/128, E); LDS = 2 buf x Wd[32][128] f32 = 32KB
__global__ __launch_bounds__(256) void k_moe_down(
    const ushort_t* __restrict__ act, const float* __restrict__ wd_all,
    const int* __restrict__ cnt, const int* __restrict__ lpair,
    float* __restrict__ out4)
{
  __shared__ float lds[2][32*128];
  __shared__ int s_pair[64];
  const int e = blockIdx.y;
  int m = cnt[e];
  if (m == 0) return;
  if (m > 64) m = 64;
  const int tid = threadIdx.x, wave = tid >> 6, lane = tid & 63;
  const int ln15 = lane & 15, kg = lane >> 4;
  if (tid < 64) s_pair[tid] = (tid < m) ? lpair[e*64 + tid] : 0;
  const int col0 = blockIdx.x * 128;
  const float* gsd = wd_all + (size_t)e * ((size_t)F_ * H_) + col0;
  const int srl = lane >> 5, scl = (lane & 31) * 4;
  const int r0 = wave * 8;

  const ushort_t* ap[4];
  #pragma unroll
  for (int rt = 0; rt < 4; ++rt)
    ap[rt] = act + ((size_t)e*64 + rt*16 + ln15) * F_ + kg*8;  // padded rows: poison but finite; discarded

  f32x4 ac[4][2];
  #pragma unroll
  for (int i = 0; i < 4; ++i) { ac[i][0]=zero4(); ac[i][1]=zero4(); }

  #pragma unroll
  for (int i2 = 0; i2 < 4; ++i2) {
    int r = r0 + i2*2;
    gload16(gsd + (size_t)(r + srl)*H_ + scl, &lds[0][r*128]);
  }
  __syncthreads();

  int cur = 0;
  for (int k0 = 0; k0 < F_; k0 += 32) {
    const int nxt = cur ^ 1;
    if (k0 + 32 < F_) {
      const float* gd = gsd + (size_t)(k0+32) * H_;
      #pragma unroll
      for (int i2 = 0; i2 < 4; ++i2) {
        int r = r0 + i2*2;
        gload16(gd + (size_t)(r + srl)*H_ + scl, &lds[nxt][r*128]);
      }
    }
    bf16x8 a[4];
    #pragma unroll
    for (int rt = 0; rt < 4; ++rt) a[rt] = loada(ap[rt] + k0);
    const float* lw = &lds[cur][wave*32 + ln15 + kg*8*128];
    bf16x8 b0 = ldsb(lw), b1 = ldsb(lw + 16);
    #pragma unroll
    for (int rt = 0; rt < 4; ++rt) {
      ac[rt][0] = MFMA(a[rt], b0, ac[rt][0]);
      ac[rt][1] = MFMA(a[rt], b1, ac[rt][1]);
    }
    __syncthreads();
    cur = nxt;
  }

  #pragma unroll
  for (int rt = 0; rt < 4; ++rt)
    #pragma unroll
    for (int nt = 0; nt < 2; ++nt)
      #pragma unroll
      for (int j = 0; j < 4; ++j) {
        int r = rt*16 + kg*4 + j;
        if (r < m)
          out4[(size_t)s_pair[r] * H_ + col0 + wave*32 + nt*16 + ln15] = ac[rt][nt][j];
      }
}

// ---------------- K5: shared gate/up (unchanged this round) -----------------------
__global__ __launch_bounds__(256) void k_sh_gu(
    const ushort_t* __restrict__ xb, const float* __restrict__ swg,
    const float* __restrict__ swu, ushort_t* __restrict__ acts)
{
  const int tid = threadIdx.x, wave = tid >> 6, lane = tid & 63;
  const int ln15 = lane & 15, kg = lane >> 4;
  const int fb = blockIdx.x * 16;
  const int rowb = wave * 64;
  const ushort_t* ap[4];
  #pragma unroll
  for (int mt = 0; mt < 4; ++mt) ap[mt] = xb + (size_t)(rowb + mt*16 + ln15) * H_ + kg*8;
  const float* pg = swg + (size_t)(kg*8) * FS_ + fb + ln15;
  const float* pu = swu + (size_t)(kg*8) * FS_ + fb + ln15;
  f32x4 ag[4], au[4];
  for (int i = 0; i < 4; ++i) { ag[i] = zero4(); au[i] = zero4(); }
  for (int k0 = 0; k0 < H_; k0 += 32) {
    bf16x8 bg = loadb(pg, FS_);
    bf16x8 bu = loadb(pu, FS_);
    #pragma unroll
    for (int mt = 0; mt < 4; ++mt) {
      bf16x8 a = loada(ap[mt] + k0);
      ag[mt] = MFMA(a, bg, ag[mt]);
      au[mt] = MFMA(a, bu, au[mt]);
    }
    pg += 32*FS_; pu += 32*FS_;
  }
  #pragma unroll
  for (int mt = 0; mt < 4; ++mt)
    #pragma unroll
    for (int j = 0; j < 4; ++j) {
      int row = rowb + mt*16 + kg*4 + j;
      float g = ag[mt][j], u = au[mt][j];
      acts[(size_t)row * FS_ + fb + ln15] = rne1(g / (1.f + __expf(-g)) * u);
    }
}

// ---------------- K6: shared down (unchanged this round) --------------------------
__global__ __launch_bounds__(256) void k_sh_down(
    const ushort_t* __restrict__ acts, const float* __restrict__ swd,
    float* __restrict__ acc2)
{
  const int tid = threadIdx.x, wave = tid >> 6, lane = tid & 63;
  const int ln15 = lane & 15, kg = lane >> 4;
  const int hb = blockIdx.x * 16;
  const int kh = blockIdx.y;
  const int rowb = wave * 64;
  const ushort_t* ap[4];
  #pragma unroll
  for (int mt = 0; mt < 4; ++mt)
    ap[mt] = acts + (size_t)(rowb + mt*16 + ln15) * FS_ + kh*2816 + kg*8;
  const float* pb = swd + (size_t)(kh*2816 + kg*8) * H_ + hb + ln15;
  f32x4 ac[4];
  for (int i = 0; i < 4; ++i) ac[i] = zero4();
  for (int k0 = 0; k0 < 2816; k0 += 32) {
    bf16x8 b = loadb(pb, H_);
    #pragma unroll
    for (int mt = 0; mt < 4; ++mt) {
      bf16x8 a = loada(ap[mt] + k0);
      ac[mt] = MFMA(a, b, ac[mt]);
    }
    pb += 32*H_;
  }
  #pragma unroll
  for (int mt = 0; mt < 4; ++mt)
    #pragma unroll
    for (int j = 0; j < 4; ++j) {
      int row = rowb + mt*16 + kg*4 + j;
      acc2[((size_t)kh * T_ + row) * H_ + hb + ln15] = ac[mt][j];
    }
}

// ---------------- K7: combine -----------------------------------------------------
__global__ __launch_bounds__(256) void k_final(
    const float* __restrict__ acc2, const float* __restrict__ out4,
    const float* __restrict__ sig, float* __restrict__ out)
{
  const int idx = blockIdx.x * blockDim.x + threadIdx.x;
  const int t = idx >> 9;
  const int h = (idx & 511) * 4;
  const float4 s0 = *(const float4*)(acc2 + (size_t)t * H_ + h);
  const float4 s1 = *(const float4*)(acc2 + ((size_t)T_ + t) * H_ + h);
  const float sg = sig[t];
  float ox = sg * (s0.x + s1.x), oy = sg * (s0.y + s1.y);
  float oz = sg * (s0.z + s1.z), ow = sg * (s0.w + s1.w);
  #pragma unroll
  for (int k = 0; k < 4; ++k) {
    const float4 e4 = *(const float4*)(out4 + (size_t)(t*4 + k) * H_ + h);
    ox += e4.x; oy += e4.y; oz += e4.z; ow += e4.w;
  }
  float4 o; o.x = ox; o.y = oy; o.z = oz; o.w = ow;
  *(float4*)(out + (size_t)t * H_ + h) = o;
}

// ---------------- launch -----------------------------------------------------------
extern "C" void kernel_launch(void* const* d_in, const int* in_sizes, int n_in,
                              void* d_out, int out_size, void* d_ws, size_t ws_size,
                              hipStream_t stream)
{
  (void)in_sizes; (void)n_in; (void)out_size; (void)ws_size;
  const float* x   = (const float*)d_in[0];
  const float* gw  = (const float*)d_in[1];
  const float* wg  = (const float*)d_in[2];
  const float* wu  = (const float*)d_in[3];
  const float* wd  = (const float*)d_in[4];
  const float* swg = (const float*)d_in[5];
  const float* swu = (const float*)d_in[6];
  const float* swd = (const float*)d_in[7];
  const float* sgw = (const float*)d_in[8];

  char* ws = (char*)d_ws;
  ushort_t* xb    = (ushort_t*)(ws);                 // 256*2048*2        = 1,048,576
  ushort_t* act   = (ushort_t*)(ws + 1048576);       // 60*64*1408*2     = 10,813,440
  ushort_t* acts  = (ushort_t*)(ws + 11862016);      // 256*5632*2       = 2,883,584
  float*    out4  = (float*)   (ws + 14745600);      // 1024*2048*4      = 8,388,608
  float*    acc2  = (float*)   (ws + 23134208);      // 2*256*2048*4     = 4,194,304
  float*    sig   = (float*)   (ws + 27328512);      // 256*4
  int*      tkidx = (int*)     (ws + 27329536);      // 256*4*4
  float*    tkval = (float*)   (ws + 27333632);      // 256*4*4
  int*      cnt   = (int*)     (ws + 27337728);      // 60*4 (pad 256)
  int*      ltok  = (int*)     (ws + 27337984);      // 60*64*4
  int*      lpair = (int*)     (ws + 27353344);      // 60*64*4
  float*    lwt   = (float*)   (ws + 27368704);      // 60*64*4

  k_router  <<<T_, 256, 0, stream>>>(x, gw, sgw, xb, tkidx, tkval, sig);
  k_lists   <<<1, 64, 0, stream>>>(tkidx, tkval, cnt, ltok, lpair, lwt);
  k_moe_gu  <<<dim3(F_/128, E_), 256, 0, stream>>>(xb, wg, wu, cnt, ltok, lwt, act);
  k_moe_down<<<dim3(H_/128, E_), 256, 0, stream>>>(act, wd, cnt, lpair, out4);
  k_sh_gu   <<<dim3(FS_/16), 256, 0, stream>>>(xb, swg, swu, acts);
  k_sh_down <<<dim3(H_/16, 2), 256, 0, stream>>>(acts, swd, acc2);
  k_final   <<<512, 256, 0, stream>>>(acc2, out4, sig, (float*)d_out);
}

// Round 6
// 671.779 us; speedup vs baseline: 1.5330x; 1.1892x over previous
//
#include <hip/hip_runtime.h>
#include <hip/hip_bf16.h>
#include <stdint.h>

typedef unsigned short ushort_t;
typedef uint32_t u32;
typedef __attribute__((ext_vector_type(8))) __bf16 bf16x8;
typedef __attribute__((ext_vector_type(8))) unsigned short u16x8;
typedef __attribute__((ext_vector_type(4))) float f32x4;

#define T_  256
#define H_  2048
#define E_  60
#define F_  1408
#define FS_ 5632

__device__ __forceinline__ u32 rne2(float lo, float hi){
  u32 a = __builtin_bit_cast(u32, lo);
  u32 b = __builtin_bit_cast(u32, hi);
  a += 0x7FFFu + ((a >> 16) & 1u);
  b += 0x7FFFu + ((b >> 16) & 1u);
  return (a >> 16) | (b & 0xFFFF0000u);
}
__device__ __forceinline__ ushort_t rne1(float f){
  u32 a = __builtin_bit_cast(u32, f);
  a += 0x7FFFu + ((a >> 16) & 1u);
  return (ushort_t)(a >> 16);
}
__device__ __forceinline__ f32x4 zero4(){ f32x4 z; z[0]=0.f; z[1]=0.f; z[2]=0.f; z[3]=0.f; return z; }

// LDS f32 tile -> bf16x8 B-fragment, row stride = S floats
__device__ __forceinline__ bf16x8 ldsbS(const float* p, const int S){
  union { u32 u[4]; bf16x8 v; } cv;
  cv.u[0] = rne2(p[0],   p[S]);
  cv.u[1] = rne2(p[2*S], p[3*S]);
  cv.u[2] = rne2(p[4*S], p[5*S]);
  cv.u[3] = rne2(p[6*S], p[7*S]);
  return cv.v;
}
__device__ __forceinline__ bf16x8 loada(const ushort_t* p){
  return __builtin_bit_cast(bf16x8, *(const u16x8*)p);
}
__device__ __forceinline__ void gload16(const float* g, float* l){
  __builtin_amdgcn_global_load_lds(
      (const __attribute__((address_space(1))) void*)g,
      (__attribute__((address_space(3))) void*)l, 16, 0, 0);
}
#define MFMA(a,b,c) __builtin_amdgcn_mfma_f32_16x16x32_bf16((a),(b),(c),0,0,0)

// counted-vmcnt pipeline primitives (T3+T4, plain HIP)
#define VMW(n)  asm volatile("s_waitcnt vmcnt(" #n ")" ::: "memory")
#define BARM()  asm volatile("s_barrier" ::: "memory")
#define SCH()   __builtin_amdgcn_sched_barrier(0)

// ---------------- K1: router -------------------------------------------------------
__global__ __launch_bounds__(256) void k_router(
    const float* __restrict__ x, const float* __restrict__ gw,
    const float* __restrict__ sgw, ushort_t* __restrict__ xb,
    int* __restrict__ tk_idx, float* __restrict__ tk_val, float* __restrict__ sig)
{
  const int t = blockIdx.x, tid = threadIdx.x;
  const float* xr = x + (size_t)t * H_;
  {
    const float4 v0 = *(const float4*)(xr + tid*8);
    const float4 v1 = *(const float4*)(xr + tid*8 + 4);
    u32* dst = (u32*)(xb + (size_t)t*H_ + tid*8);
    dst[0] = rne2(v0.x, v0.y); dst[1] = rne2(v0.z, v0.w);
    dst[2] = rne2(v1.x, v1.y); dst[3] = rne2(v1.z, v1.w);
  }
  __shared__ float s_part[4][64];
  __shared__ float s_logit[64];
  __shared__ float s_red[256];
  const int e = tid & 63, q = tid >> 6;
  float p = 0.f;
  if (e < E_) {
    const float* g = gw + e;
    for (int h = q*512; h < q*512 + 512; ++h) p += xr[h] * g[h*E_];
  }
  s_part[q][e] = p;
  float sp = 0.f;
  for (int h = tid; h < H_; h += 256) sp += xr[h] * sgw[h];
  s_red[tid] = sp;
  __syncthreads();
  if (tid < 64) s_logit[tid] = s_part[0][tid] + s_part[1][tid] + s_part[2][tid] + s_part[3][tid];
  for (int s = 128; s > 0; s >>= 1) {
    if (tid < s) s_red[tid] += s_red[tid + s];
    __syncthreads();
  }
  if (tid == 0) {
    sig[t] = 1.f / (1.f + expf(-s_red[0]));
    float mx = -3.4e38f;
    for (int i = 0; i < E_; ++i) mx = fmaxf(mx, s_logit[i]);
    float sum = 0.f;
    for (int i = 0; i < E_; ++i) sum += expf(s_logit[i] - mx);
    for (int k = 0; k < 4; ++k) {
      float bv = -3.4e38f; int bi = 0;
      for (int i = 0; i < E_; ++i) { float v = s_logit[i]; if (v > bv) { bv = v; bi = i; } }
      tk_idx[t*4 + k] = bi;
      tk_val[t*4 + k] = expf(bv - mx) / sum;
      s_logit[bi] = -3.4e38f;
    }
  }
}

// ---------------- K2: per-expert token lists ---------------------------------------
__global__ void k_lists(const int* __restrict__ tk_idx, const float* __restrict__ tk_val,
                        int* __restrict__ cnt, int* __restrict__ ltok,
                        int* __restrict__ lpair, float* __restrict__ lwt)
{
  const int e = threadIdx.x;
  if (e >= E_) return;
  int c = 0;
  for (int t = 0; t < T_; ++t) {
    #pragma unroll
    for (int k = 0; k < 4; ++k) {
      int ei = tk_idx[t*4 + k];
      if (ei == e && c < 64) {
        ltok[e*64 + c] = t;
        lpair[e*64 + c] = t*4 + k;
        lwt[e*64 + c] = tk_val[t*4 + k];
        ++c;
      }
    }
  }
  cnt[e] = c;
}

// ---------------- K3: MoE gate/up, counted-vmcnt pipeline. M=64, N=128 -------------
// per tile: 8 gload16 + 4 A-loads = 12 vmem -> vmcnt(12)
__global__ __launch_bounds__(256) void k_moe_gu(
    const ushort_t* __restrict__ xb, const float* __restrict__ wg_all,
    const float* __restrict__ wu_all, const int* __restrict__ cnt,
    const int* __restrict__ ltok, const float* __restrict__ lwt,
    ushort_t* __restrict__ act)
{
  __shared__ float lds[2][2*32*128];
  const int e = blockIdx.y;
  int m = cnt[e];
  if (m == 0) return;
  if (m > 64) m = 64;
  const int tid = threadIdx.x, wave = tid >> 6, lane = tid & 63;
  const int ln15 = lane & 15, kg = lane >> 4;
  const int col0 = blockIdx.x * 128;
  const size_t wbase = (size_t)e * ((size_t)H_ * F_) + col0;
  const float* gsg = wg_all + wbase + (size_t)(lane >> 5) * F_ + (lane & 31) * 4;
  const float* gsu = wu_all + wbase + (size_t)(lane >> 5) * F_ + (lane & 31) * 4;
  const int r0 = wave * 8;

  const ushort_t* ap[4];
  #pragma unroll
  for (int rt = 0; rt < 4; ++rt) {
    int row = rt*16 + ln15;
    int tok = ltok[e*64 + (row < m ? row : m-1)];
    ap[rt] = xb + (size_t)tok * H_ + kg*8;
  }

  f32x4 ag[4][2], au[4][2];
  #pragma unroll
  for (int i = 0; i < 4; ++i) { ag[i][0]=zero4(); ag[i][1]=zero4(); au[i][0]=zero4(); au[i][1]=zero4(); }
  bf16x8 a0[4], a1[4];

#define GU_STAGE(B, K0) do { \
    _Pragma("unroll") for (int i2 = 0; i2 < 4; ++i2) { \
      int r_ = r0 + i2*2; \
      gload16(gsg + (size_t)(K0 + r_) * F_, &lds[B][r_*128]); \
      gload16(gsu + (size_t)(K0 + r_) * F_, &lds[B][4096 + r_*128]); \
    } } while(0)
#define GU_ALOAD(D, K0) do { \
    _Pragma("unroll") for (int rt = 0; rt < 4; ++rt) D[rt] = loada(ap[rt] + (K0)); } while(0)
#define GU_COMPUTE(B, A) do { \
    const float* lg_ = &lds[B][kg*1024 + wave*32 + ln15]; \
    bf16x8 bg0_ = ldsbS(lg_, 128), bg1_ = ldsbS(lg_ + 16, 128); \
    bf16x8 bu0_ = ldsbS(lg_ + 4096, 128), bu1_ = ldsbS(lg_ + 4112, 128); \
    _Pragma("unroll") for (int rt = 0; rt < 4; ++rt) { \
      ag[rt][0] = MFMA(A[rt], bg0_, ag[rt][0]); \
      ag[rt][1] = MFMA(A[rt], bg1_, ag[rt][1]); \
      au[rt][0] = MFMA(A[rt], bu0_, au[rt][0]); \
      au[rt][1] = MFMA(A[rt], bu1_, au[rt][1]); \
    } } while(0)

  GU_ALOAD(a0, 0);  GU_STAGE(0, 0);
  GU_ALOAD(a1, 32); GU_STAGE(1, 32);
  for (int t = 0; t + 2 < 64; t += 2) {
    VMW(12); BARM(); SCH();
    GU_COMPUTE(0, a0);
    BARM();
    GU_ALOAD(a0, (t+2)*32); GU_STAGE(0, (t+2)*32);
    VMW(12); BARM(); SCH();
    GU_COMPUTE(1, a1);
    BARM();
    GU_ALOAD(a1, (t+3)*32); GU_STAGE(1, (t+3)*32);
  }
  VMW(12); BARM(); SCH();
  GU_COMPUTE(0, a0);
  VMW(0); BARM(); SCH();
  GU_COMPUTE(1, a1);

  #pragma unroll
  for (int rt = 0; rt < 4; ++rt)
    #pragma unroll
    for (int nt = 0; nt < 2; ++nt)
      #pragma unroll
      for (int j = 0; j < 4; ++j) {
        int r = rt*16 + kg*4 + j;
        if (r < m) {
          float wt = lwt[e*64 + r];
          float g = ag[rt][nt][j], u = au[rt][nt][j];
          float a = g / (1.f + __expf(-g)) * u * wt;
          act[((size_t)e*64 + r) * F_ + col0 + wave*32 + nt*16 + ln15] = rne1(a);
        }
      }
}

// ---------------- K4: MoE down, counted-vmcnt pipeline. M=64, N=128 ----------------
// per tile: 4 gload16 + 4 A-loads = 8 vmem -> vmcnt(8); NT = 44
__global__ __launch_bounds__(256) void k_moe_down(
    const ushort_t* __restrict__ act, const float* __restrict__ wd_all,
    const int* __restrict__ cnt, const int* __restrict__ lpair,
    float* __restrict__ out4)
{
  __shared__ float lds[2][32*128];
  __shared__ int s_pair[64];
  const int e = blockIdx.y;
  int m = cnt[e];
  if (m == 0) return;
  if (m > 64) m = 64;
  const int tid = threadIdx.x, wave = tid >> 6, lane = tid & 63;
  const int ln15 = lane & 15, kg = lane >> 4;
  if (tid < 64) s_pair[tid] = (tid < m) ? lpair[e*64 + tid] : 0;
  const int col0 = blockIdx.x * 128;
  const float* gsd = wd_all + (size_t)e * ((size_t)F_ * H_) + col0
                   + (size_t)(lane >> 5) * H_ + (lane & 31) * 4;
  const int r0 = wave * 8;

  const ushort_t* ap[4];
  #pragma unroll
  for (int rt = 0; rt < 4; ++rt)
    ap[rt] = act + ((size_t)e*64 + rt*16 + ln15) * F_ + kg*8;

  f32x4 ac[4][2];
  #pragma unroll
  for (int i = 0; i < 4; ++i) { ac[i][0]=zero4(); ac[i][1]=zero4(); }
  bf16x8 a0[4], a1[4];

#define DN_STAGE(B, K0) do { \
    _Pragma("unroll") for (int i2 = 0; i2 < 4; ++i2) { \
      int r_ = r0 + i2*2; \
      gload16(gsd + (size_t)(K0 + r_) * H_, &lds[B][r_*128]); \
    } } while(0)
#define DN_ALOAD(D, K0) do { \
    _Pragma("unroll") for (int rt = 0; rt < 4; ++rt) D[rt] = loada(ap[rt] + (K0)); } while(0)
#define DN_COMPUTE(B, A) do { \
    const float* lw_ = &lds[B][kg*1024 + wave*32 + ln15]; \
    bf16x8 b0_ = ldsbS(lw_, 128), b1_ = ldsbS(lw_ + 16, 128); \
    _Pragma("unroll") for (int rt = 0; rt < 4; ++rt) { \
      ac[rt][0] = MFMA(A[rt], b0_, ac[rt][0]); \
      ac[rt][1] = MFMA(A[rt], b1_, ac[rt][1]); \
    } } while(0)

  DN_ALOAD(a0, 0);  DN_STAGE(0, 0);
  DN_ALOAD(a1, 32); DN_STAGE(1, 32);
  for (int t = 0; t + 2 < 44; t += 2) {
    VMW(8); BARM(); SCH();
    DN_COMPUTE(0, a0);
    BARM();
    DN_ALOAD(a0, (t+2)*32); DN_STAGE(0, (t+2)*32);
    VMW(8); BARM(); SCH();
    DN_COMPUTE(1, a1);
    BARM();
    DN_ALOAD(a1, (t+3)*32); DN_STAGE(1, (t+3)*32);
  }
  VMW(8); BARM(); SCH();
  DN_COMPUTE(0, a0);
  VMW(0); BARM(); SCH();
  DN_COMPUTE(1, a1);

  #pragma unroll
  for (int rt = 0; rt < 4; ++rt)
    #pragma unroll
    for (int nt = 0; nt < 2; ++nt)
      #pragma unroll
      for (int j = 0; j < 4; ++j) {
        int r = rt*16 + kg*4 + j;
        if (r < m)
          out4[(size_t)s_pair[r] * H_ + col0 + wave*32 + nt*16 + ln15] = ac[rt][nt][j];
      }
}

// ---------------- K5: shared gate/up. M=256 (waves split rows), N=32 ---------------
// per tile: 2 gload16 + 4 A = 6 vmem -> vmcnt(6); NT = 64; grid 176
__global__ __launch_bounds__(256) void k_sh_gu(
    const ushort_t* __restrict__ xb, const float* __restrict__ swg,
    const float* __restrict__ swu, ushort_t* __restrict__ acts)
{
  __shared__ float lds[2][2048];   // [buf][ Wg 32x32 | Wu 32x32 ]
  const int tid = threadIdx.x, wave = tid >> 6, lane = tid & 63;
  const int ln15 = lane & 15, kg = lane >> 4;
  const int cb = blockIdx.x * 32;
  const int rowb = wave * 64;
  const int r0 = wave * 8;
  const float* gsg = swg + (size_t)(lane >> 3) * FS_ + cb + (lane & 7) * 4;
  const float* gsu = swu + (size_t)(lane >> 3) * FS_ + cb + (lane & 7) * 4;

  const ushort_t* ap[4];
  #pragma unroll
  for (int rt = 0; rt < 4; ++rt)
    ap[rt] = xb + (size_t)(rowb + rt*16 + ln15) * H_ + kg*8;

  f32x4 ag[4][2], au[4][2];
  #pragma unroll
  for (int i = 0; i < 4; ++i) { ag[i][0]=zero4(); ag[i][1]=zero4(); au[i][0]=zero4(); au[i][1]=zero4(); }
  bf16x8 a0[4], a1[4];

#define SG_STAGE(B, K0) do { \
    gload16(gsg + (size_t)(K0 + r0) * FS_, &lds[B][r0*32]); \
    gload16(gsu + (size_t)(K0 + r0) * FS_, &lds[B][1024 + r0*32]); \
  } while(0)
#define SG_ALOAD(D, K0) do { \
    _Pragma("unroll") for (int rt = 0; rt < 4; ++rt) D[rt] = loada(ap[rt] + (K0)); } while(0)
#define SG_COMPUTE(B, A) do { \
    const float* lg_ = &lds[B][kg*256 + ln15]; \
    bf16x8 bg0_ = ldsbS(lg_, 32), bg1_ = ldsbS(lg_ + 16, 32); \
    bf16x8 bu0_ = ldsbS(lg_ + 1024, 32), bu1_ = ldsbS(lg_ + 1040, 32); \
    _Pragma("unroll") for (int rt = 0; rt < 4; ++rt) { \
      ag[rt][0] = MFMA(A[rt], bg0_, ag[rt][0]); \
      ag[rt][1] = MFMA(A[rt], bg1_, ag[rt][1]); \
      au[rt][0] = MFMA(A[rt], bu0_, au[rt][0]); \
      au[rt][1] = MFMA(A[rt], bu1_, au[rt][1]); \
    } } while(0)

  SG_ALOAD(a0, 0);  SG_STAGE(0, 0);
  SG_ALOAD(a1, 32); SG_STAGE(1, 32);
  for (int t = 0; t + 2 < 64; t += 2) {
    VMW(6); BARM(); SCH();
    SG_COMPUTE(0, a0);
    BARM();
    SG_ALOAD(a0, (t+2)*32); SG_STAGE(0, (t+2)*32);
    VMW(6); BARM(); SCH();
    SG_COMPUTE(1, a1);
    BARM();
    SG_ALOAD(a1, (t+3)*32); SG_STAGE(1, (t+3)*32);
  }
  VMW(6); BARM(); SCH();
  SG_COMPUTE(0, a0);
  VMW(0); BARM(); SCH();
  SG_COMPUTE(1, a1);

  #pragma unroll
  for (int rt = 0; rt < 4; ++rt)
    #pragma unroll
    for (int nt = 0; nt < 2; ++nt)
      #pragma unroll
      for (int j = 0; j < 4; ++j) {
        int row = rowb + rt*16 + kg*4 + j;
        float g = ag[rt][nt][j], u = au[rt][nt][j];
        acts[(size_t)row * FS_ + cb + nt*16 + ln15] = rne1(g / (1.f + __expf(-g)) * u);
      }
}

// ---------------- K6: shared down. M=256, N=64, K-split 4 -> acc4 ------------------
// per tile: 2 gload16 + 4 A = 6 vmem -> vmcnt(6); NT = 44; grid (32, 4)
__global__ __launch_bounds__(256) void k_sh_down(
    const ushort_t* __restrict__ acts, const float* __restrict__ swd,
    float* __restrict__ acc4)
{
  __shared__ float lds[2][2048];   // [buf][ Wd 32x64 ]
  const int tid = threadIdx.x, wave = tid >> 6, lane = tid & 63;
  const int ln15 = lane & 15, kg = lane >> 4;
  const int cb = blockIdx.x * 64;
  const int kh = blockIdx.y;       // k in [kh*1408, +1408)
  const int rowb = wave * 64;
  const int r0 = wave * 8;
  const float* gsd = swd + (size_t)(kh*1408) * H_ + cb
                   + (size_t)(lane >> 4) * H_ + (lane & 15) * 4;

  const ushort_t* ap[4];
  #pragma unroll
  for (int rt = 0; rt < 4; ++rt)
    ap[rt] = acts + (size_t)(rowb + rt*16 + ln15) * FS_ + kh*1408 + kg*8;

  f32x4 ac[4][4];
  #pragma unroll
  for (int i = 0; i < 4; ++i)
    #pragma unroll
    for (int c = 0; c < 4; ++c) ac[i][c] = zero4();
  bf16x8 a0[4], a1[4];

#define SD_STAGE(B, K0) do { \
    gload16(gsd + (size_t)(K0 + r0) * H_,     &lds[B][r0*64]); \
    gload16(gsd + (size_t)(K0 + r0 + 4) * H_, &lds[B][(r0+4)*64]); \
  } while(0)
#define SD_ALOAD(D, K0) do { \
    _Pragma("unroll") for (int rt = 0; rt < 4; ++rt) D[rt] = loada(ap[rt] + (K0)); } while(0)
#define SD_COMPUTE(B, A) do { \
    const float* lw_ = &lds[B][kg*512 + ln15]; \
    bf16x8 b0_ = ldsbS(lw_, 64),      b1_ = ldsbS(lw_ + 16, 64); \
    bf16x8 b2_ = ldsbS(lw_ + 32, 64), b3_ = ldsbS(lw_ + 48, 64); \
    _Pragma("unroll") for (int rt = 0; rt < 4; ++rt) { \
      ac[rt][0] = MFMA(A[rt], b0_, ac[rt][0]); \
      ac[rt][1] = MFMA(A[rt], b1_, ac[rt][1]); \
      ac[rt][2] = MFMA(A[rt], b2_, ac[rt][2]); \
      ac[rt][3] = MFMA(A[rt], b3_, ac[rt][3]); \
    } } while(0)

  SD_ALOAD(a0, 0);  SD_STAGE(0, 0);
  SD_ALOAD(a1, 32); SD_STAGE(1, 32);
  for (int t = 0; t + 2 < 44; t += 2) {
    VMW(6); BARM(); SCH();
    SD_COMPUTE(0, a0);
    BARM();
    SD_ALOAD(a0, (t+2)*32); SD_STAGE(0, (t+2)*32);
    VMW(6); BARM(); SCH();
    SD_COMPUTE(1, a1);
    BARM();
    SD_ALOAD(a1, (t+3)*32); SD_STAGE(1, (t+3)*32);
  }
  VMW(6); BARM(); SCH();
  SD_COMPUTE(0, a0);
  VMW(0); BARM(); SCH();
  SD_COMPUTE(1, a1);

  #pragma unroll
  for (int rt = 0; rt < 4; ++rt)
    #pragma unroll
    for (int c = 0; c < 4; ++c)
      #pragma unroll
      for (int j = 0; j < 4; ++j) {
        int row = rowb + rt*16 + kg*4 + j;
        acc4[((size_t)kh * T_ + row) * H_ + cb + c*16 + ln15] = ac[rt][c][j];
      }
}

// ---------------- K7: combine ------------------------------------------------------
__global__ __launch_bounds__(256) void k_final(
    const float* __restrict__ acc4, const float* __restrict__ out4,
    const float* __restrict__ sig, float* __restrict__ out)
{
  const int idx = blockIdx.x * blockDim.x + threadIdx.x;
  const int t = idx >> 9;
  const int h = (idx & 511) * 4;
  float ox = 0.f, oy = 0.f, oz = 0.f, ow = 0.f;
  #pragma unroll
  for (int s = 0; s < 4; ++s) {
    const float4 v = *(const float4*)(acc4 + ((size_t)s * T_ + t) * H_ + h);
    ox += v.x; oy += v.y; oz += v.z; ow += v.w;
  }
  const float sg = sig[t];
  ox *= sg; oy *= sg; oz *= sg; ow *= sg;
  #pragma unroll
  for (int k = 0; k < 4; ++k) {
    const float4 e4 = *(const float4*)(out4 + (size_t)(t*4 + k) * H_ + h);
    ox += e4.x; oy += e4.y; oz += e4.z; ow += e4.w;
  }
  float4 o; o.x = ox; o.y = oy; o.z = oz; o.w = ow;
  *(float4*)(out + (size_t)t * H_ + h) = o;
}

// ---------------- launch -----------------------------------------------------------
extern "C" void kernel_launch(void* const* d_in, const int* in_sizes, int n_in,
                              void* d_out, int out_size, void* d_ws, size_t ws_size,
                              hipStream_t stream)
{
  (void)in_sizes; (void)n_in; (void)out_size; (void)ws_size;
  const float* x   = (const float*)d_in[0];
  const float* gw  = (const float*)d_in[1];
  const float* wg  = (const float*)d_in[2];
  const float* wu  = (const float*)d_in[3];
  const float* wd  = (const float*)d_in[4];
  const float* swg = (const float*)d_in[5];
  const float* swu = (const float*)d_in[6];
  const float* swd = (const float*)d_in[7];
  const float* sgw = (const float*)d_in[8];

  char* ws = (char*)d_ws;
  ushort_t* xb    = (ushort_t*)(ws);                 // 1,048,576
  ushort_t* act   = (ushort_t*)(ws + 1048576);       // 10,813,440
  ushort_t* acts  = (ushort_t*)(ws + 11862016);      // 2,883,584
  float*    out4  = (float*)   (ws + 14745600);      // 8,388,608
  float*    acc4  = (float*)   (ws + 23134208);      // 8,388,608
  float*    sig   = (float*)   (ws + 31522816);      // 1,024
  int*      tkidx = (int*)     (ws + 31523840);      // 4,096
  float*    tkval = (float*)   (ws + 31527936);      // 4,096
  int*      cnt   = (int*)     (ws + 31532032);      // 256
  int*      ltok  = (int*)     (ws + 31532288);      // 15,360
  int*      lpair = (int*)     (ws + 31547648);      // 15,360
  float*    lwt   = (float*)   (ws + 31563008);      // 15,360

  k_router  <<<T_, 256, 0, stream>>>(x, gw, sgw, xb, tkidx, tkval, sig);
  k_lists   <<<1, 64, 0, stream>>>(tkidx, tkval, cnt, ltok, lpair, lwt);
  k_moe_gu  <<<dim3(F_/128, E_), 256, 0, stream>>>(xb, wg, wu, cnt, ltok, lwt, act);
  k_moe_down<<<dim3(H_/128, E_), 256, 0, stream>>>(act, wd, cnt, lpair, out4);
  k_sh_gu   <<<dim3(FS_/32), 256, 0, stream>>>(xb, swg, swu, acts);
  k_sh_down <<<dim3(H_/64, 4), 256, 0, stream>>>(acts, swd, acc4);
  k_final   <<<512, 256, 0, stream>>>(acc4, out4, sig, (float*)d_out);
}